// Round 2
// baseline (439.132 us; speedup 1.0000x reference)
//
#include <hip/hip_runtime.h>

#define B_DIM   2048
#define IN_DIM  4096
#define OUT_DIM 4096
#define FAN     64

// R7: R5's proven 112-VGPR codegen (4-row 8B cells, ds_read_b64, rolling
// addrs/wv window) at DOUBLE the occupancy: 512-thread blocks, 64 KB LDS
// (two 32 KB buffers) -> 2 blocks/CU = 16 waves/CU (R5: 8).
// R6 failed because 1024-thread blocks spilled addrs/wv to scratch
// (VGPR 112->64, FETCH 16.5->98.6 MB). 512 threads keeps per-thread
// pressure identical to R5; __launch_bounds__(512,4) caps VGPR at 128.
//  Phase 1: pack fp32 -> bf16 4-ROW cells in d_ws. Tile t = rows 4t..4t+3,
//    cell (t,c) = 8 B at ws[(t*4096+c)*8]: dword0 = rows(0,1), dword1 = rows(2,3).
//  Phase 2: grid 64 bsegs x 8 oblocks = 512 blocks (2/CU), 512 threads.
//    Per block: 32 batch rows = 8 tiles, software-pipelined A/B stages with
//    compile-time LDS offset (0 / 32768) so addresses stay rematerializable.

typedef float v2f __attribute__((ext_vector_type(2)));

__device__ __forceinline__ unsigned bf16_rne(float f) {
    unsigned u = __float_as_uint(f);
    return (u + 0x7fffu + ((u >> 16) & 1u)) >> 16;   // round-to-nearest-even bf16
}

// ---------------- Phase 1: pack fp32 -> bf16 4-row cells ----------------
__global__ __launch_bounds__(256) void pack_kernel(
    const float* __restrict__ input, uint4* __restrict__ wsp)
{
    const int idx = blockIdx.x * 256 + threadIdx.x;   // [0, 1048576) cell-pairs
    const int t   = idx >> 11;                        // tile [0,512)
    const int c0  = (idx & 2047) << 1;                // column pair base

    const float* p = input + (size_t)t * 4 * IN_DIM + c0;
    const float2 r0 = *reinterpret_cast<const float2*>(p + 0 * IN_DIM);
    const float2 r1 = *reinterpret_cast<const float2*>(p + 1 * IN_DIM);
    const float2 r2 = *reinterpret_cast<const float2*>(p + 2 * IN_DIM);
    const float2 r3 = *reinterpret_cast<const float2*>(p + 3 * IN_DIM);

    uint4 q;                                          // cells c0 and c0+1
    q.x = bf16_rne(r0.x) | (bf16_rne(r1.x) << 16);
    q.y = bf16_rne(r2.x) | (bf16_rne(r3.x) << 16);
    q.z = bf16_rne(r0.y) | (bf16_rne(r1.y) << 16);
    q.w = bf16_rne(r2.y) | (bf16_rne(r3.y) << 16);

    wsp[(size_t)t * 2048 + (c0 >> 1)] = q;
}

// ---------------- Phase 2: pipelined gather + accumulate ----------------
__global__ __launch_bounds__(512, 4) void condensed_kernel(
    const uint4* __restrict__ wsp,
    const float* __restrict__ weight,
    const float* __restrict__ bias,
    const int*   __restrict__ mask,
    float*       __restrict__ out)
{
    __shared__ __align__(16) uint4 lds[4096];         // 64 KB = 2 x 2048 uint4

    const int tid     = threadIdx.x;
    const int o       = blockIdx.y * 512 + tid;
    const int tbase   = blockIdx.x * 8;               // 8 tiles of 4 rows
    const int rowbase = blockIdx.x * 32;              // 32 batch rows per block

    // ---- idx -> LDS byte addresses (cell = 8 B) + weights, in registers ----
    unsigned addrs[FAN];
    float    wv[FAN];
    {
        const int4*   mv = reinterpret_cast<const int4*>(mask)     + o * (FAN / 4);
        const float4* wp = reinterpret_cast<const float4*>(weight) + o * (FAN / 4);
        #pragma unroll
        for (int j = 0; j < FAN / 4; ++j) {
            int4   m4 = mv[j];
            float4 w4 = wp[j];
            addrs[4*j+0] = (unsigned)m4.x << 3;
            addrs[4*j+1] = (unsigned)m4.y << 3;
            addrs[4*j+2] = (unsigned)m4.z << 3;
            addrs[4*j+3] = (unsigned)m4.w << 3;
            wv[4*j+0] = w4.x;
            wv[4*j+1] = w4.y;
            wv[4*j+2] = w4.z;
            wv[4*j+3] = w4.w;
        }
    }
    const float bv = bias[o];

    // ---- prologue: DMA tile 0 -> buf0 (32 KB, 4 x 16 B per thread) ----
    {
        const uint4* src = wsp + (size_t)tbase * 2048 + tid;
        #pragma unroll
        for (int it = 0; it < 4; ++it) {
            __builtin_amdgcn_global_load_lds(
                (const __attribute__((address_space(1))) unsigned*)(src + it * 512),
                (__attribute__((address_space(3))) unsigned*)(lds + it * 512 + tid),
                16, 0, 0);
        }
    }
    __syncthreads();

    const char* ldsb = reinterpret_cast<const char*>(lds);

    for (int hp = 0; hp < 4; ++hp) {
        const int h0 = hp * 2;

        // ==== stage A: prefetch tile h0+1 -> buf1, compute buf0 (offset 0) ====
        {
            const uint4* src = wsp + (size_t)(tbase + h0 + 1) * 2048 + tid;
            #pragma unroll
            for (int it = 0; it < 4; ++it) {
                __builtin_amdgcn_global_load_lds(
                    (const __attribute__((address_space(1))) unsigned*)(src + it * 512),
                    (__attribute__((address_space(3))) unsigned*)(lds + 2048 + it * 512 + tid),
                    16, 0, 0);
            }
        }
        {
            v2f a01 = {0.f, 0.f}, a23 = {0.f, 0.f};
            #pragma unroll
            for (int j = 0; j < FAN; ++j) {
                const uint2 g = *reinterpret_cast<const uint2*>(ldsb + addrs[j]);
                const v2f w2 = {wv[j], wv[j]};
                v2f v;
                v.x = __uint_as_float(g.x << 16);
                v.y = __uint_as_float(g.x & 0xffff0000u);
                a01 = __builtin_elementwise_fma(v, w2, a01);
                v.x = __uint_as_float(g.y << 16);
                v.y = __uint_as_float(g.y & 0xffff0000u);
                a23 = __builtin_elementwise_fma(v, w2, a23);
            }
            float* op = out + (size_t)(rowbase + 4 * h0) * OUT_DIM + o;
            op[0 * OUT_DIM] = a01.x + bv;
            op[1 * OUT_DIM] = a01.y + bv;
            op[2 * OUT_DIM] = a23.x + bv;
            op[3 * OUT_DIM] = a23.y + bv;
        }
        __syncthreads();   // buf0 free; DMA(h0+1 -> buf1) drained

        // ==== stage B: prefetch tile h0+2 -> buf0, compute buf1 (offset 32768) ====
        if (hp < 3) {
            const uint4* src = wsp + (size_t)(tbase + h0 + 2) * 2048 + tid;
            #pragma unroll
            for (int it = 0; it < 4; ++it) {
                __builtin_amdgcn_global_load_lds(
                    (const __attribute__((address_space(1))) unsigned*)(src + it * 512),
                    (__attribute__((address_space(3))) unsigned*)(lds + it * 512 + tid),
                    16, 0, 0);
            }
        }
        {
            v2f a01 = {0.f, 0.f}, a23 = {0.f, 0.f};
            #pragma unroll
            for (int j = 0; j < FAN; ++j) {
                // +32768 = buf1; compile-time constant folds into ds_read offset
                const uint2 g = *reinterpret_cast<const uint2*>(ldsb + 32768 + addrs[j]);
                const v2f w2 = {wv[j], wv[j]};
                v2f v;
                v.x = __uint_as_float(g.x << 16);
                v.y = __uint_as_float(g.x & 0xffff0000u);
                a01 = __builtin_elementwise_fma(v, w2, a01);
                v.x = __uint_as_float(g.y << 16);
                v.y = __uint_as_float(g.y & 0xffff0000u);
                a23 = __builtin_elementwise_fma(v, w2, a23);
            }
            float* op = out + (size_t)(rowbase + 4 * h0 + 4) * OUT_DIM + o;
            op[0 * OUT_DIM] = a01.x + bv;
            op[1 * OUT_DIM] = a01.y + bv;
            op[2 * OUT_DIM] = a23.x + bv;
            op[3 * OUT_DIM] = a23.y + bv;
        }
        __syncthreads();   // buf1 free; DMA(h0+2 -> buf0) drained
    }
}

extern "C" void kernel_launch(void* const* d_in, const int* in_sizes, int n_in,
                              void* d_out, int out_size, void* d_ws, size_t ws_size,
                              hipStream_t stream) {
    const float* input  = (const float*)d_in[0];
    const float* weight = (const float*)d_in[1];
    const float* bias   = (const float*)d_in[2];
    const int*   mask   = (const int*)d_in[3];
    float*       out    = (float*)d_out;
    uint4*       wsp    = (uint4*)d_ws;               // needs 16 MiB

    pack_kernel<<<4096, 256, 0, stream>>>(input, wsp);
    dim3 grid(64, 8);   // 64 bsegs x 8 oblocks = 512 blocks = 2/CU (64 KB LDS)
    condensed_kernel<<<grid, 512, 0, stream>>>(wsp, weight, bias, mask, out);
}

// Round 3
// 134.670 us; speedup vs baseline: 3.2608x; 3.2608x over previous
//
#include <hip/hip_runtime.h>

#define B_DIM   2048
#define IN_DIM  4096
#define OUT_DIM 4096
#define FAN     64

// R8: R5's exact 112-VGPR codegen regime (256 threads, launch_bounds(256,2),
// 4-row 8B cells, ds_read_b64 gather, same prologue/inner loop) with
// occupancy from BLOCK COUNT instead of block size:
//   - single 32 KB LDS buffer (one 4-row tile; irreducible, mask spans all
//     4096 columns) -> 4 blocks/CU resident (VGPR-limited: floor(512/112)=4
//     waves/SIMD; LDS would allow 5). 16 waves/CU vs R5's 8.
//   - no intra-block double-buffer; the per-tile DMA drain (~1k cyc) is
//     covered by the other 3 resident blocks' compute (inter-block TLP).
// R6/R7 lesson: launch_bounds min-waves=4 caps VGPR at 128 -> allocator
// spills addrs[64]/wv[64] (VGPR 112->64, FETCH 16.5->620 MB). Stay at (256,2).
// Grid (64,16): wg id = x+64y -> all 16 oblocks of a bseg share id mod 8 ->
// same XCD -> per-XCD L2 working set 2 MB <= 4 MB. No swizzle needed.

typedef float v2f __attribute__((ext_vector_type(2)));

__device__ __forceinline__ unsigned bf16_rne(float f) {
    unsigned u = __float_as_uint(f);
    return (u + 0x7fffu + ((u >> 16) & 1u)) >> 16;   // round-to-nearest-even bf16
}

// ---------------- Phase 1: pack fp32 -> bf16 4-row cells ----------------
__global__ __launch_bounds__(256) void pack_kernel(
    const float* __restrict__ input, uint4* __restrict__ wsp)
{
    const int idx = blockIdx.x * 256 + threadIdx.x;   // [0, 1048576) cell-pairs
    const int t   = idx >> 11;                        // tile [0,512)
    const int c0  = (idx & 2047) << 1;                // column pair base

    const float* p = input + (size_t)t * 4 * IN_DIM + c0;
    const float2 r0 = *reinterpret_cast<const float2*>(p + 0 * IN_DIM);
    const float2 r1 = *reinterpret_cast<const float2*>(p + 1 * IN_DIM);
    const float2 r2 = *reinterpret_cast<const float2*>(p + 2 * IN_DIM);
    const float2 r3 = *reinterpret_cast<const float2*>(p + 3 * IN_DIM);

    uint4 q;                                          // cells c0 and c0+1
    q.x = bf16_rne(r0.x) | (bf16_rne(r1.x) << 16);
    q.y = bf16_rne(r2.x) | (bf16_rne(r3.x) << 16);
    q.z = bf16_rne(r0.y) | (bf16_rne(r1.y) << 16);
    q.w = bf16_rne(r2.y) | (bf16_rne(r3.y) << 16);

    wsp[(size_t)t * 2048 + (c0 >> 1)] = q;
}

// ---------------- Phase 2: gather + accumulate, 4 blocks/CU ----------------
__global__ __launch_bounds__(256, 2) void condensed_kernel(
    const uint4* __restrict__ wsp,
    const float* __restrict__ weight,
    const float* __restrict__ bias,
    const int*   __restrict__ mask,
    float*       __restrict__ out)
{
    __shared__ __align__(16) uint4 lds[2048];         // 32 KB = one 4-row tile

    const int tid     = threadIdx.x;
    const int o       = blockIdx.y * 256 + tid;
    const int tbase   = blockIdx.x * 8;               // 8 tiles of 4 rows
    const int rowbase = blockIdx.x * 32;              // 32 batch rows per block

    // ---- idx -> LDS byte addresses (cell = 8 B) + weights, in registers ----
    unsigned addrs[FAN];
    float    wv[FAN];
    {
        const int4*   mv = reinterpret_cast<const int4*>(mask)     + o * (FAN / 4);
        const float4* wp = reinterpret_cast<const float4*>(weight) + o * (FAN / 4);
        #pragma unroll
        for (int j = 0; j < FAN / 4; ++j) {
            int4   m4 = mv[j];
            float4 w4 = wp[j];
            addrs[4*j+0] = (unsigned)m4.x << 3;
            addrs[4*j+1] = (unsigned)m4.y << 3;
            addrs[4*j+2] = (unsigned)m4.z << 3;
            addrs[4*j+3] = (unsigned)m4.w << 3;
            wv[4*j+0] = w4.x;
            wv[4*j+1] = w4.y;
            wv[4*j+2] = w4.z;
            wv[4*j+3] = w4.w;
        }
    }
    const float bv = bias[o];

    const char* ldsb = reinterpret_cast<const char*>(lds);

    for (int t = 0; t < 8; ++t) {
        if (t) __syncthreads();            // all waves done reading buffer

        // DMA tile t -> buffer (8 x 16 B per thread = 32 KB)
        {
            const uint4* src = wsp + (size_t)(tbase + t) * 2048 + tid;
            #pragma unroll
            for (int it = 0; it < 8; ++it) {
                __builtin_amdgcn_global_load_lds(
                    (const __attribute__((address_space(1))) unsigned*)(src + it * 256),
                    (__attribute__((address_space(3))) unsigned*)(lds + it * 256 + tid),
                    16, 0, 0);
            }
        }
        __syncthreads();                   // vmcnt(0) drain + visibility

        // gather + accumulate 4 rows
        {
            v2f a01 = {0.f, 0.f}, a23 = {0.f, 0.f};
            #pragma unroll
            for (int j = 0; j < FAN; ++j) {
                const uint2 g = *reinterpret_cast<const uint2*>(ldsb + addrs[j]);
                const v2f w2 = {wv[j], wv[j]};
                v2f v;
                v.x = __uint_as_float(g.x << 16);
                v.y = __uint_as_float(g.x & 0xffff0000u);
                a01 = __builtin_elementwise_fma(v, w2, a01);
                v.x = __uint_as_float(g.y << 16);
                v.y = __uint_as_float(g.y & 0xffff0000u);
                a23 = __builtin_elementwise_fma(v, w2, a23);
            }
            float* op = out + (size_t)(rowbase + 4 * t) * OUT_DIM + o;
            op[0 * OUT_DIM] = a01.x + bv;
            op[1 * OUT_DIM] = a01.y + bv;
            op[2 * OUT_DIM] = a23.x + bv;
            op[3 * OUT_DIM] = a23.y + bv;
        }
    }
}

extern "C" void kernel_launch(void* const* d_in, const int* in_sizes, int n_in,
                              void* d_out, int out_size, void* d_ws, size_t ws_size,
                              hipStream_t stream) {
    const float* input  = (const float*)d_in[0];
    const float* weight = (const float*)d_in[1];
    const float* bias   = (const float*)d_in[2];
    const int*   mask   = (const int*)d_in[3];
    float*       out    = (float*)d_out;
    uint4*       wsp    = (uint4*)d_ws;               // needs 16 MiB

    pack_kernel<<<4096, 256, 0, stream>>>(input, wsp);
    dim3 grid(64, 16);  // 1024 blocks = 4/CU (32 KB LDS, 112 VGPR) -- 16 waves/CU
    condensed_kernel<<<grid, 256, 0, stream>>>(wsp, weight, bias, mask, out);
}